// Round 9
// baseline (218.392 us; speedup 1.0000x reference)
//
#include <hip/hip_runtime.h>
#include <hip/hip_bf16.h>

#define BS    128
#define NCIN  64
#define NCOUT 64
#define LLEN  8192
#define NK    3
#define NR    8
#define NEMB  256
#define NHID  256
#define WPS   (NCOUT * NCIN * NK)   // 12288 weights per sample
#define NT    256                   // l-positions per tile
#define NTILE 8                     // tiles per conv block (chunk = 2048 l)

typedef __attribute__((ext_vector_type(4)))  float  f32x4;
typedef __attribute__((ext_vector_type(16))) float  f32x16;
typedef __attribute__((ext_vector_type(8)))  __bf16 bf16x8;

// Static device scratch (fully rewritten every call).
__device__ float  g_h[2][BS * NHID]; // post-GELU hidden
__device__ float  g_A[BS * 512];     // A factors [b][ci*8+r]
__device__ float  g_B[BS * 1536];    // B factors [b][r*192+co*3+k]
__device__ __bf16 g_Wb[BS * WPS];    // W_eff bf16 [b][k*4096+co*64+ci]

// ---------------------------------------------------------------------------
// Kernel 1a: hidden layer. 256 blocks = (branch, sample).
// ---------------------------------------------------------------------------
__global__ __launch_bounds__(256) void mlp_hid(
    const float* __restrict__ a_emb, const float* __restrict__ b_emb,
    const float* __restrict__ A_w1, const float* __restrict__ A_b1,
    const float* __restrict__ A_g,  const float* __restrict__ A_beta,
    const float* __restrict__ B_w1, const float* __restrict__ B_b1,
    const float* __restrict__ B_g,  const float* __restrict__ B_beta)
{
    __shared__ __align__(16) float emb_s[NEMB];

    const int t      = threadIdx.x;
    const int branch = blockIdx.x >> 7;
    const int b      = blockIdx.x & 127;

    const float* emb = (branch ? b_emb : a_emb) + (size_t)b * NEMB;
    const float* w1  = branch ? B_w1 : A_w1;
    const float* b1  = branch ? B_b1 : A_b1;
    const float* gg  = branch ? B_g  : A_g;
    const float* bt  = branch ? B_beta : A_beta;

    emb_s[t] = emb[t];
    __syncthreads();

    float acc = b1[t];
    const f32x4* wr = (const f32x4*)(w1 + (size_t)t * NEMB);
    const f32x4* es = (const f32x4*)emb_s;
    for (int e = 0; e < NEMB / 4; ++e) {
        f32x4 w = wr[e], a = es[e];
        acc += w[0]*a[0] + w[1]*a[1] + w[2]*a[2] + w[3]*a[3];
    }
    float h = acc * (gg[t] * (1.0f / sqrtf(1.0f + 1e-5f))) + bt[t];
    h = 0.5f * h * (1.0f + erff(h * 0.70710678118654752f));
    g_h[branch][(size_t)b * NHID + t] = h;
}

// ---------------------------------------------------------------------------
// Kernel 1b: output layers. 1024 blocks = (sample, o-chunk of 256).
// oo 0..1 -> A factors (512), oo 2..7 -> B factors (1536).
// ---------------------------------------------------------------------------
__global__ __launch_bounds__(256) void mlp_out(
    const float* __restrict__ A_w2, const float* __restrict__ A_b2,
    const float* __restrict__ B_w2, const float* __restrict__ B_b2)
{
    __shared__ __align__(16) float h_s[NHID];

    const int t      = threadIdx.x;
    const int b      = blockIdx.x >> 3;
    const int oo     = blockIdx.x & 7;
    const int branch = (oo >= 2) ? 1 : 0;

    h_s[t] = g_h[branch][(size_t)b * NHID + t];
    __syncthreads();

    const int o = branch ? (oo - 2) * 256 + t : oo * 256 + t;
    const float* w2 = branch ? B_w2 : A_w2;
    const float* b2 = branch ? B_b2 : A_b2;

    float acc = b2[o];
    const f32x4* wr = (const f32x4*)(w2 + (size_t)o * NHID);
    const f32x4* hs = (const f32x4*)h_s;
    for (int e = 0; e < NHID / 4; ++e) {
        f32x4 w = wr[e], h = hs[e];
        acc += w[0]*h[0] + w[1]*h[1] + w[2]*h[2] + w[3]*h[3];
    }
    if (branch) g_B[(size_t)b * 1536 + o] = acc;
    else        g_A[(size_t)b * 512  + o] = acc;
}

// ---------------------------------------------------------------------------
// Kernel 2: assemble W_eff = base_w + A·B  (bf16, [b][k*4096+co*64+ci]).
// ---------------------------------------------------------------------------
__global__ __launch_bounds__(256) void assemble_kernel(const float* __restrict__ base_w)
{
    const int b  = blockIdx.x >> 2;
    const int q  = blockIdx.x & 3;
    const int t  = threadIdx.x;
    const int ci = t & 63;

    float Ar[NR];
    const f32x4* Ap = (const f32x4*)(g_A + (size_t)b * 512 + ci * NR);
    f32x4 a0 = Ap[0], a1 = Ap[1];
    Ar[0]=a0[0]; Ar[1]=a0[1]; Ar[2]=a0[2]; Ar[3]=a0[3];
    Ar[4]=a1[0]; Ar[5]=a1[1]; Ar[6]=a1[2]; Ar[7]=a1[3];

    const float* Bp = g_B + (size_t)b * 1536;
    for (int i = 0; i < 12; ++i) {
        const int w  = q * 3072 + i * 256 + t;
        const int k  = w >> 12;
        const int co = (w >> 6) & 63;
        float v = base_w[(size_t)(co * 64 + ci) * 3 + k];
        #pragma unroll
        for (int r = 0; r < NR; ++r) v += Ar[r] * Bp[r * 192 + co * 3 + k];
        g_Wb[(size_t)b * WPS + w] = (__bf16)v;
    }
}

// ---------------------------------------------------------------------------
// Kernel 3: software-pipelined persistent conv. 512 blocks = (b, 2048-l chunk),
// exactly 2 blocks/CU. Per block: W frags + base_b loaded once; loop over 8
// tiles of 256 l with double-buffered LDS: prefetch t+1 to regs || MFMA tile t
// || direct full-line stores || ds_write t+1 || barrier.
// LDS tile: [lp][ci] bf16, blk-swizzle (ci>>3)^(lp&7)^((lp>>3)&7).
// ---------------------------------------------------------------------------
__global__ __launch_bounds__(256, 2) void conv_kernel(
    const float* __restrict__ X, const float* __restrict__ base_b,
    float* __restrict__ out)
{
    __shared__ __align__(16) __bf16 xts[2][(NT + 2) * 64];

    const int t     = threadIdx.x;
    const int b     = blockIdx.x >> 2;     // 4 chunks per sample
    const int chunk = blockIdx.x & 3;
    const int lane  = t & 63;
    const int wave  = t >> 6;
    const int l31   = lane & 31;
    const int khalf = lane >> 5;
    const int wco   = wave >> 1;           // which 32 co
    const int wl    = wave & 1;            // which 128 l
    const int lb    = t & 31;              // staging: 8-l block
    const int cb    = t >> 5;              // staging: 8-ci block

    const float* xbase = X + (size_t)b * NCIN * LLEN;

    // ---- per-block constants: W fragments + base_b (loaded once, 8x reuse) ----
    bf16x8 af[3][4];
    {
        const __bf16* wb = g_Wb + (size_t)b * WPS + (wco * 32 + l31) * 64 + khalf * 8;
        #pragma unroll
        for (int tap = 0; tap < 3; ++tap)
            #pragma unroll
            for (int c16 = 0; c16 < 4; ++c16)
                af[tap][c16] = *(const bf16x8*)(wb + tap * 4096 + c16 * 16);
    }
    float bb_reg[16];
    #pragma unroll
    for (int reg = 0; reg < 16; ++reg)
        bb_reg[reg] = base_b[wco * 32 + (reg & 3) + 8 * (reg >> 2) + 4 * khalf];

    // ---- pipeline state ----
    f32x4 v[8][2];
    float hv = 0.0f;

    auto prefetch = [&](int lt) {   // stage tile starting at l-position lt into regs
        const float* xb = xbase + lt + lb * 8;
        #pragma unroll
        for (int c = 0; c < 8; ++c) {
            const float* xr = xb + (size_t)(cb * 8 + c) * LLEN;
            v[c][0] = *(const f32x4*)(xr);
            v[c][1] = *(const f32x4*)(xr + 4);
        }
        if (t < 128) {              // halo (pad = 1)
            const int ci    = t & 63;
            const int right = t >> 6;
            const int gl    = right ? (lt + NT) : (lt - 1);
            hv = (gl >= 0 && gl < LLEN) ? xbase[(size_t)ci * LLEN + gl] : 0.0f;
        }
    };
    auto dswrite = [&](int p) {     // regs -> LDS buffer p (conflict-free b128)
        __bf16* xp = xts[p];
        #pragma unroll
        for (int j = 0; j < 8; ++j) {
            const int lp = lb * 8 + j + 1;
            bf16x8 w;
            #pragma unroll
            for (int c = 0; c < 8; ++c) w[c] = (__bf16)v[c][j >> 2][j & 3];
            const int blk = cb ^ (lp & 7) ^ ((lp >> 3) & 7);
            *(bf16x8*)(xp + lp * 64 + blk * 8) = w;
        }
        if (t < 128) {
            const int ci  = t & 63;
            const int lp  = (t >> 6) ? (NT + 1) : 0;
            const int blk = (ci >> 3) ^ (lp & 7) ^ ((lp >> 3) & 7);
            xp[lp * 64 + blk * 8 + (ci & 7)] = (__bf16)hv;
        }
    };

    // ---- prologue ----
    const int l0 = chunk * (NT * NTILE);
    prefetch(l0);
    dswrite(0);
    __syncthreads();

    // ---- main pipelined loop ----
    int p = 0;
    for (int tt = 0; tt < NTILE; ++tt) {
        const int lt = l0 + tt * NT;
        if (tt < NTILE - 1) prefetch(lt + NT);   // VMEM in flight under compute

        const __bf16* xp = xts[p];
        f32x16 acc[4] = {};
        #pragma unroll
        for (int tap = 0; tap < 3; ++tap)
            #pragma unroll
            for (int c16 = 0; c16 < 4; ++c16)
                #pragma unroll
                for (int n = 0; n < 4; ++n) {
                    const int R   = wl * 128 + n * 32 + l31 + tap;
                    const int blk = (c16 * 2 + khalf) ^ (R & 7) ^ ((R >> 3) & 7);
                    bf16x8 bfr = *(const bf16x8*)(xp + R * 64 + blk * 8);
                    acc[n] = __builtin_amdgcn_mfma_f32_32x32x16_bf16(af[tap][c16], bfr, acc[n], 0, 0, 0);
                }

        // direct stores: each instr = 2 co-rows x 128 B contiguous (full lines)
        #pragma unroll
        for (int reg = 0; reg < 16; ++reg) {
            const int co = wco * 32 + (reg & 3) + 8 * (reg >> 2) + 4 * khalf;
            float* op = out + (size_t)(b * NCOUT + co) * LLEN + lt + wl * 128 + l31;
            #pragma unroll
            for (int n = 0; n < 4; ++n)
                op[n * 32] = acc[n][reg] + bb_reg[reg];
        }

        if (tt < NTILE - 1) dswrite(p ^ 1);
        __syncthreads();
        p ^= 1;
    }
}

// ---------------------------------------------------------------------------
extern "C" void kernel_launch(void* const* d_in, const int* in_sizes, int n_in,
                              void* d_out, int out_size, void* d_ws, size_t ws_size,
                              hipStream_t stream)
{
    const float* X      = (const float*)d_in[0];
    const float* a_emb  = (const float*)d_in[1];
    const float* b_emb  = (const float*)d_in[2];
    const float* A_w1   = (const float*)d_in[3];
    const float* A_b1   = (const float*)d_in[4];
    const float* A_g    = (const float*)d_in[5];
    const float* A_beta = (const float*)d_in[6];
    const float* A_w2   = (const float*)d_in[7];
    const float* A_b2   = (const float*)d_in[8];
    const float* B_w1   = (const float*)d_in[9];
    const float* B_b1   = (const float*)d_in[10];
    const float* B_g    = (const float*)d_in[11];
    const float* B_beta = (const float*)d_in[12];
    const float* B_w2   = (const float*)d_in[13];
    const float* B_b2   = (const float*)d_in[14];
    const float* base_w = (const float*)d_in[15];
    const float* base_b = (const float*)d_in[16];

    float* out = (float*)d_out;   // reference output dtype is float32

    mlp_hid<<<2 * BS, 256, 0, stream>>>(a_emb, b_emb,
        A_w1, A_b1, A_g, A_beta, B_w1, B_b1, B_g, B_beta);

    mlp_out<<<8 * BS, 256, 0, stream>>>(A_w2, A_b2, B_w2, B_b2);

    assemble_kernel<<<4 * BS, 256, 0, stream>>>(base_w);

    conv_kernel<<<4 * BS, 256, 0, stream>>>(X, base_b, out);
}